// Round 1
// baseline (140.038 us; speedup 1.0000x reference)
//
#include <hip/hip_runtime.h>

// Problem constants (match reference setup_inputs)
#define BB   4
#define NN   100000
#define CC   128
#define RESO 128
#define PIX  (RESO * RESO)   // 16384 pixels per (b, plane)

// ---------------------------------------------------------------------------
// Kernel 1: collapse channel dim with fc_w ->  ws[plane][b][y][x]
//   ws[plane*BB*PIX + b*PIX + idx] = sum_c fc_w[c] * img[b][c][idx]
// Grid: (BB*PIX/256, 3 planes). Fully coalesced reads (threads adjacent in
// pixel index, per-c loads are 256B/wave contiguous segments).
// ---------------------------------------------------------------------------
__global__ __launch_bounds__(256) void reduce_planes_k(
    const float* __restrict__ cxz, const float* __restrict__ cxy,
    const float* __restrict__ cyz, const float* __restrict__ fcw,
    float* __restrict__ ws)
{
    __shared__ float w[CC];
    const int t = threadIdx.x;
    if (t < CC) w[t] = fcw[t];
    __syncthreads();

    const int plane = blockIdx.y;
    const float* __restrict__ img = (plane == 0) ? cxz : (plane == 1) ? cxy : cyz;

    const int pix = blockIdx.x * 256 + t;       // 0 .. BB*PIX-1
    const int b   = pix >> 14;                  // / PIX
    const int idx = pix & (PIX - 1);

    const float* __restrict__ base = img + ((size_t)b * CC) * PIX + idx;

    float sum = 0.0f;
#pragma unroll 16
    for (int c = 0; c < CC; ++c) {
        sum = fmaf(w[c], base[(size_t)c * PIX], sum);
    }
    ws[(size_t)plane * (BB * PIX) + pix] = sum;
}

// ---------------------------------------------------------------------------
// Kernel 2: per-point bilinear sample of the 3 reduced planes + linear head.
// ---------------------------------------------------------------------------
__device__ __forceinline__ float bilin(const float* __restrict__ pb,
                                       float a, float bcoord)
{
    const float DIVC = 1.0f + 0.1f + 1e-5f;      // 1.10001
    const float HI   = 1.0f - 1e-5f;

    float u = a / DIVC + 0.5f;
    float v = bcoord / DIVC + 0.5f;
    u = fminf(fmaxf(u, 0.0f), HI);
    v = fminf(fmaxf(v, 0.0f), HI);

    float x = u * (float)(RESO - 1);
    float y = v * (float)(RESO - 1);
    float xf = floorf(x), yf = floorf(y);
    float wx = x - xf,    wy = y - yf;

    int x0 = (int)xf, y0 = (int)yf;
    x0 = min(max(x0, 0), RESO - 1);
    y0 = min(max(y0, 0), RESO - 1);
    int x1 = min(x0 + 1, RESO - 1);
    int y1 = min(y0 + 1, RESO - 1);

    float v00 = pb[y0 * RESO + x0];
    float v01 = pb[y0 * RESO + x1];
    float v10 = pb[y1 * RESO + x0];
    float v11 = pb[y1 * RESO + x1];

    return v00 * (1.0f - wx) * (1.0f - wy)
         + v01 * wx * (1.0f - wy)
         + v10 * (1.0f - wx) * wy
         + v11 * wx * wy;
}

__global__ __launch_bounds__(256) void sample_k(
    const float* __restrict__ p, const float* __restrict__ ws,
    const float* __restrict__ fcw, const float* __restrict__ fcb,
    float* __restrict__ out)
{
    const int i = blockIdx.x * 256 + threadIdx.x;   // over B*N
    if (i >= BB * NN) return;

    const float p0 = p[3 * i + 0];
    const float p1 = p[3 * i + 1];
    const float p2 = p[3 * i + 2];

    const int b = i / NN;
    const float* __restrict__ w0 = ws + 0 * (BB * PIX) + b * PIX;  // xz
    const float* __restrict__ w1 = ws + 1 * (BB * PIX) + b * PIX;  // xy
    const float* __restrict__ w2 = ws + 2 * (BB * PIX) + b * PIX;  // yz

    float s = bilin(w0, p0, p2)    // c_xz: (u=p0, v=p2)
            + bilin(w1, p0, p1)    // c_xy: (u=p0, v=p1)
            + bilin(w2, p1, p2);   // c_yz: (u=p1, v=p2)

    s += p0 * fcw[CC + 0] + p1 * fcw[CC + 1] + p2 * fcw[CC + 2] + fcb[0];

    out[i] = s;
}

// ---------------------------------------------------------------------------
extern "C" void kernel_launch(void* const* d_in, const int* in_sizes, int n_in,
                              void* d_out, int out_size, void* d_ws, size_t ws_size,
                              hipStream_t stream) {
    const float* p   = (const float*)d_in[0];
    const float* cxz = (const float*)d_in[1];
    const float* cxy = (const float*)d_in[2];
    const float* cyz = (const float*)d_in[3];
    const float* fcw = (const float*)d_in[4];
    const float* fcb = (const float*)d_in[5];
    float* out = (float*)d_out;
    float* ws  = (float*)d_ws;   // needs 3*BB*PIX*4 = 786432 bytes

    dim3 g1(BB * PIX / 256, 3);
    reduce_planes_k<<<g1, 256, 0, stream>>>(cxz, cxy, cyz, fcw, ws);

    const int npts = BB * NN;
    sample_k<<<(npts + 255) / 256, 256, 0, stream>>>(p, ws, fcw, fcb, out);
}